// Round 1
// baseline (512.387 us; speedup 1.0000x reference)
//
#include <hip/hip_runtime.h>
#include <hip/hip_bf16.h>
#include <math.h>

typedef __bf16 bf16;
typedef __attribute__((ext_vector_type(8))) __bf16 bf16x8;
typedef __attribute__((ext_vector_type(4))) __bf16 bf16x4;
typedef __attribute__((ext_vector_type(4))) float f32x4;

#define HDIM 1024
#define NHEAD 16
#define HD 64
#define FFDIM 4096
#define BATCH 2
#define SEQ 2048
#define M_TOK 4096  // BATCH*SEQ

static __device__ __forceinline__ void async_load16(const bf16* g, bf16* l) {
  __builtin_amdgcn_global_load_lds(
      (const __attribute__((address_space(1))) void*)g,
      (__attribute__((address_space(3))) void*)l, 16, 0, 0);
}

// ---------------------------------------------------------------- cast f32->bf16
__global__ __launch_bounds__(256)
void cast_f32_to_bf16(const float* __restrict__ in, bf16* __restrict__ out)
{
  const size_t i = ((size_t)blockIdx.x * 256 + threadIdx.x) * 4;
  f32x4 v = *(const f32x4*)(in + i);
  bf16x4 o;
#pragma unroll
  for (int j = 0; j < 4; ++j) o[j] = (bf16)v[j];
  *(bf16x4*)(out + i) = o;
}

// ------------------------------------------------- transpose+cast: in[R][C] f32 -> out[C][R] bf16
__global__ __launch_bounds__(256)
void transpose_cast(const float* __restrict__ in, bf16* __restrict__ out, int R, int C)
{
  __shared__ float tile[32][33];
  const int tx = threadIdx.x & 31, ty = threadIdx.x >> 5; // ty 0..7
  const int c0 = blockIdx.x * 32, r0 = blockIdx.y * 32;
#pragma unroll
  for (int i = 0; i < 32; i += 8)
    tile[ty + i][tx] = in[(size_t)(r0 + ty + i) * C + c0 + tx];
  __syncthreads();
#pragma unroll
  for (int i = 0; i < 32; i += 8)
    out[(size_t)(c0 + ty + i) * R + r0 + tx] = (bf16)tile[tx][ty + i];
}

// ---------------------------------------------------------------- GEMM  C = A @ Bt^T + bias
// A[M][K] bf16 row-major, Bt[N][K] bf16 row-major (i.e. B transposed).
// 128x128 tile, BK=64, 256 threads (2x2 waves, each 64x64 via 4x4 mfma_16x16x32 tiles).
// LDS layout: tile[row][64] bf16, 8 chunks of 16B per row, chunk XOR-swizzled by (row&7).
// EPI: 0=bf16 out, 1=f32 out, 2=gelu->bf16, 3=V-transpose out (Vt[b,h][d][s])
template<int EPI>
__global__ __launch_bounds__(256)
void gemm_bt(const bf16* __restrict__ A, const bf16* __restrict__ Bt,
             const float* __restrict__ bias, void* __restrict__ Cout,
             int M, int N, int K)
{
  __shared__ __align__(16) bf16 As[128 * 64];
  __shared__ __align__(16) bf16 Bs[128 * 64];
  const int t = threadIdx.x;
  const int wave = t >> 6, lane = t & 63;
  const int lm = lane & 15, qd = lane >> 4;
  const int wm = (wave >> 1) * 64, wn = (wave & 1) * 64;
  const int bm = blockIdx.y * 128, bn = blockIdx.x * 128;

  f32x4 acc[4][4] = {};

  const int srow = t >> 3;  // 0..31 (+32 per round)
  const int schk = t & 7;

  for (int k0 = 0; k0 < K; k0 += 64) {
#pragma unroll
    for (int r = 0; r < 4; ++r) {
      const int row = r * 32 + srow;
      const int chunk = schk ^ (row & 7);
      async_load16(A + (size_t)(bm + row) * K + (k0 + chunk * 8),
                   (bf16*)((char*)As + r * 4096 + t * 16));
    }
#pragma unroll
    for (int r = 0; r < 4; ++r) {
      const int row = r * 32 + srow;
      const int chunk = schk ^ (row & 7);
      async_load16(Bt + (size_t)(bn + row) * K + (k0 + chunk * 8),
                   (bf16*)((char*)Bs + r * 4096 + t * 16));
    }
    __syncthreads();
#pragma unroll
    for (int ks = 0; ks < 2; ++ks) {
      bf16x8 av[4], bv[4];
#pragma unroll
      for (int mt = 0; mt < 4; ++mt) {
        const int row = wm + mt * 16 + lm;
        const int chunk = (ks * 4 + qd) ^ (row & 7);
        av[mt] = *(const bf16x8*)(As + row * 64 + chunk * 8);
      }
#pragma unroll
      for (int nt = 0; nt < 4; ++nt) {
        const int row = wn + nt * 16 + lm;
        const int chunk = (ks * 4 + qd) ^ (row & 7);
        bv[nt] = *(const bf16x8*)(Bs + row * 64 + chunk * 8);
      }
#pragma unroll
      for (int mt = 0; mt < 4; ++mt)
#pragma unroll
        for (int nt = 0; nt < 4; ++nt)
          acc[mt][nt] = __builtin_amdgcn_mfma_f32_16x16x32_bf16(av[mt], bv[nt], acc[mt][nt], 0, 0, 0);
    }
    __syncthreads();
  }

#pragma unroll
  for (int nt = 0; nt < 4; ++nt) {
    const int col = bn + wn + nt * 16 + lm;
    const float bs = bias[col];
#pragma unroll
    for (int mt = 0; mt < 4; ++mt) {
#pragma unroll
      for (int r = 0; r < 4; ++r) {
        const int row = bm + wm + mt * 16 + qd * 4 + r;
        float v = acc[mt][nt][r] + bs;
        if (EPI == 0) {
          ((bf16*)Cout)[(size_t)row * N + col] = (bf16)v;
        } else if (EPI == 1) {
          ((float*)Cout)[(size_t)row * N + col] = v;
        } else if (EPI == 2) {
          float g = v * 0.5f * (1.0f + erff(v * 0.70710678118f));
          ((bf16*)Cout)[(size_t)row * N + col] = (bf16)g;
        } else {
          const int hh = col >> 6, dd = col & 63;
          const int bb = row >> 11, ss = row & 2047;
          ((bf16*)Cout)[(size_t)((bb * NHEAD + hh) * HD + dd) * SEQ + ss] = (bf16)v;
        }
      }
    }
  }
}

// ---------------------------------------------------------------- flash attention
// grid (SEQ/128, BATCH*NHEAD), 256 threads. Wave w handles 32 q-rows.
// Q,K: [4096][1024] bf16.  Vt: [(b*16+h)*64 + d][2048] bf16.  Aout: [4096][1024] bf16.
__global__ __launch_bounds__(256)
void attn_kernel(const bf16* __restrict__ Q, const bf16* __restrict__ Kg,
                 const bf16* __restrict__ Vt, const int* __restrict__ mask,
                 bf16* __restrict__ Aout)
{
  __shared__ __align__(16) bf16 Ks[64 * 64];
  __shared__ __align__(16) bf16 Vs[64 * 64];
  __shared__ __align__(16) bf16 Ps[4][32 * 64];
  __shared__ float madd[64];

  const int t = threadIdx.x;
  const int wave = t >> 6, lane = t & 63;
  const int lm = lane & 15, qd = lane >> 4;
  const int bh = blockIdx.y;
  const int b = bh >> 4, h = bh & 15;
  const int q0 = blockIdx.x * 128 + wave * 32;

  // Q fragments, pre-scaled by 1/sqrt(HD)=0.125 (power of two: exact in bf16)
  bf16x8 qf[2][2];
#pragma unroll
  for (int mt = 0; mt < 2; ++mt)
#pragma unroll
    for (int ks = 0; ks < 2; ++ks) {
      bf16x8 v = *(const bf16x8*)(Q + (size_t)(b * SEQ + q0 + mt * 16 + lm) * HDIM + h * HD + ks * 32 + qd * 8);
#pragma unroll
      for (int j = 0; j < 8; ++j) v[j] = (bf16)((float)v[j] * 0.125f);
      qf[mt][ks] = v;
    }

  float mrow[2][4], lrow[2][4];
  f32x4 oacc[2][4] = {};
#pragma unroll
  for (int mt = 0; mt < 2; ++mt)
#pragma unroll
    for (int r = 0; r < 4; ++r) { mrow[mt][r] = -3.0e38f; lrow[mt][r] = 0.f; }

  const int srow = t >> 3, schk = t & 7;

  for (int kv0 = 0; kv0 < SEQ; kv0 += 64) {
#pragma unroll
    for (int r = 0; r < 2; ++r) {
      const int row = r * 32 + srow;
      const int chunk = schk ^ (row & 7);
      async_load16(Kg + (size_t)(b * SEQ + kv0 + row) * HDIM + h * HD + chunk * 8,
                   (bf16*)((char*)Ks + r * 4096 + t * 16));
      async_load16(Vt + (size_t)(bh * HD + row) * SEQ + kv0 + chunk * 8,
                   (bf16*)((char*)Vs + r * 4096 + t * 16));
    }
    if (t < 64) madd[t] = (mask[b * SEQ + kv0 + t] == 1) ? 0.f : -1.0e30f;
    __syncthreads();

    // S = (Q/8) K^T
    f32x4 sacc[2][4] = {};
#pragma unroll
    for (int ks = 0; ks < 2; ++ks) {
      bf16x8 kf[4];
#pragma unroll
      for (int nt = 0; nt < 4; ++nt) {
        const int row = nt * 16 + lm;
        const int chunk = (ks * 4 + qd) ^ (row & 7);
        kf[nt] = *(const bf16x8*)(Ks + row * 64 + chunk * 8);
      }
#pragma unroll
      for (int mt = 0; mt < 2; ++mt)
#pragma unroll
        for (int nt = 0; nt < 4; ++nt)
          sacc[mt][nt] = __builtin_amdgcn_mfma_f32_16x16x32_bf16(qf[mt][ks], kf[nt], sacc[mt][nt], 0, 0, 0);
    }

    // additive mask + online softmax
#pragma unroll
    for (int mt = 0; mt < 2; ++mt) {
#pragma unroll
      for (int nt = 0; nt < 4; ++nt) {
        const float ma = madd[nt * 16 + lm];
#pragma unroll
        for (int r = 0; r < 4; ++r) sacc[mt][nt][r] += ma;
      }
      float alpha[4];
#pragma unroll
      for (int r = 0; r < 4; ++r) {
        float mv = fmaxf(fmaxf(sacc[mt][0][r], sacc[mt][1][r]), fmaxf(sacc[mt][2][r], sacc[mt][3][r]));
#pragma unroll
        for (int d = 1; d < 16; d <<= 1) mv = fmaxf(mv, __shfl_xor(mv, d, 64));
        const float mnew = fmaxf(mrow[mt][r], mv);
        alpha[r] = __expf(mrow[mt][r] - mnew);
        mrow[mt][r] = mnew;
      }
#pragma unroll
      for (int r = 0; r < 4; ++r) {
        float sum = 0.f;
#pragma unroll
        for (int nt = 0; nt < 4; ++nt) {
          const float p = __expf(sacc[mt][nt][r] - mrow[mt][r]);
          sacc[mt][nt][r] = p;
          sum += p;
        }
#pragma unroll
        for (int d = 1; d < 16; d <<= 1) sum += __shfl_xor(sum, d, 64);
        lrow[mt][r] = lrow[mt][r] * alpha[r] + sum;
      }
#pragma unroll
      for (int nt = 0; nt < 4; ++nt)
#pragma unroll
        for (int r = 0; r < 4; ++r)
          oacc[mt][nt][r] *= alpha[r];
      // P (C-layout) -> LDS (A-layout source), 16B-chunk swizzled
#pragma unroll
      for (int nt = 0; nt < 4; ++nt)
#pragma unroll
        for (int r = 0; r < 4; ++r) {
          const int row = mt * 16 + qd * 4 + r;
          const int col = nt * 16 + lm;
          const int ch = (col >> 3) ^ (row & 7);
          Ps[wave][row * 64 + ch * 8 + (col & 7)] = (bf16)sacc[mt][nt][r];
        }
    }
    __syncthreads();

    // O += P @ V
#pragma unroll
    for (int ks = 0; ks < 2; ++ks) {
      bf16x8 pf[2], vf[4];
#pragma unroll
      for (int mt = 0; mt < 2; ++mt) {
        const int row = mt * 16 + lm;
        const int chunk = (ks * 4 + qd) ^ (row & 7);
        pf[mt] = *(const bf16x8*)(Ps[wave] + row * 64 + chunk * 8);
      }
#pragma unroll
      for (int nt = 0; nt < 4; ++nt) {
        const int row = nt * 16 + lm;
        const int chunk = (ks * 4 + qd) ^ (row & 7);
        vf[nt] = *(const bf16x8*)(Vs + row * 64 + chunk * 8);
      }
#pragma unroll
      for (int mt = 0; mt < 2; ++mt)
#pragma unroll
        for (int nt = 0; nt < 4; ++nt)
          oacc[mt][nt] = __builtin_amdgcn_mfma_f32_16x16x32_bf16(pf[mt], vf[nt], oacc[mt][nt], 0, 0, 0);
    }
    __syncthreads();
  }

#pragma unroll
  for (int mt = 0; mt < 2; ++mt) {
    float inv[4];
#pragma unroll
    for (int r = 0; r < 4; ++r) inv[r] = 1.0f / lrow[mt][r];
#pragma unroll
    for (int nt = 0; nt < 4; ++nt)
#pragma unroll
      for (int r = 0; r < 4; ++r) {
        const int row = b * SEQ + q0 + mt * 16 + qd * 4 + r;
        const int col = h * HD + nt * 16 + lm;
        Aout[(size_t)row * HDIM + col] = (bf16)(oacc[mt][nt][r] * inv[r]);
      }
  }
}

// ---------------------------------------------------------------- layernorm over H=1024
template<int OUT_BF16>
__global__ __launch_bounds__(256)
void layernorm_k(const float* __restrict__ in, const float* __restrict__ gamma,
                 const float* __restrict__ beta, void* __restrict__ out)
{
  const int row = blockIdx.x;
  const int t = threadIdx.x;
  const float* x = in + (size_t)row * HDIM;
  f32x4 v = *(const f32x4*)(x + t * 4);
  float s = v[0] + v[1] + v[2] + v[3];
  float s2 = v[0] * v[0] + v[1] * v[1] + v[2] * v[2] + v[3] * v[3];
#pragma unroll
  for (int d = 1; d < 64; d <<= 1) { s += __shfl_xor(s, d, 64); s2 += __shfl_xor(s2, d, 64); }
  __shared__ float ss[4], ss2[4];
  const int wave = t >> 6, lane = t & 63;
  if (lane == 0) { ss[wave] = s; ss2[wave] = s2; }
  __syncthreads();
  s = ss[0] + ss[1] + ss[2] + ss[3];
  s2 = ss2[0] + ss2[1] + ss2[2] + ss2[3];
  const float mean = s * (1.0f / HDIM);
  const float var = s2 * (1.0f / HDIM) - mean * mean;
  const float rstd = rsqrtf(var + 1e-12f);
  f32x4 gv = *(const f32x4*)(gamma + t * 4);
  f32x4 bv = *(const f32x4*)(beta + t * 4);
  f32x4 y;
#pragma unroll
  for (int j = 0; j < 4; ++j) y[j] = gv[j] * (v[j] - mean) * rstd + bv[j];
  if (OUT_BF16) {
    bf16x4 o;
#pragma unroll
    for (int j = 0; j < 4; ++j) o[j] = (bf16)y[j];
    *(bf16x4*)((bf16*)out + (size_t)row * HDIM + t * 4) = o;
  } else {
    *(f32x4*)((float*)out + (size_t)row * HDIM + t * 4) = y;
  }
}

// ---------------------------------------------------------------- launch
extern "C" void kernel_launch(void* const* d_in, const int* in_sizes, int n_in,
                              void* d_out, int out_size, void* d_ws, size_t ws_size,
                              hipStream_t stream)
{
  const float* x    = (const float*)d_in[0];
  const int*   am   = (const int*)d_in[1];
  const float* Wq   = (const float*)d_in[2];
  const float* bq   = (const float*)d_in[3];
  const float* Wk   = (const float*)d_in[4];
  const float* bk   = (const float*)d_in[5];
  const float* Wv   = (const float*)d_in[6];
  const float* bv   = (const float*)d_in[7];
  const float* Wo   = (const float*)d_in[8];
  const float* bo   = (const float*)d_in[9];
  const float* ln1g = (const float*)d_in[10];
  const float* ln1b = (const float*)d_in[11];
  const float* W1   = (const float*)d_in[12];
  const float* b1   = (const float*)d_in[13];
  const float* W2   = (const float*)d_in[14];
  const float* b2   = (const float*)d_in[15];
  const float* ln2g = (const float*)d_in[16];
  const float* ln2b = (const float*)d_in[17];

  char* ws = (char*)d_ws;
  const size_t MB = 1ull << 20;
  bf16*  Xb  = (bf16*)(ws + 0 * MB);    // 8 MiB, dead after V gemm
  bf16*  WqT = (bf16*)(ws + 8 * MB);    // 2 MiB
  bf16*  WkT = (bf16*)(ws + 10 * MB);   // 2 MiB
  bf16*  WvT = (bf16*)(ws + 12 * MB);   // 2 MiB
  bf16*  WoT = (bf16*)(ws + 14 * MB);   // 2 MiB
  bf16*  W1T = (bf16*)(ws + 16 * MB);   // 8 MiB
  bf16*  W2T = (bf16*)(ws + 24 * MB);   // 8 MiB
  bf16*  Qb  = (bf16*)(ws + 32 * MB);   // 8 MiB
  bf16*  Kb  = (bf16*)(ws + 40 * MB);   // 8 MiB
  bf16*  Vtb = (bf16*)(ws + 48 * MB);   // 8 MiB
  bf16*  Ab  = (bf16*)(ws + 56 * MB);   // 8 MiB
  float* AWo = (float*)(ws + 64 * MB);  // 16 MiB
  bf16*  L1  = (bf16*)(ws + 80 * MB);   // 8 MiB   (peak: 88 MiB)
  bf16*  F1  = (bf16*)(ws + 32 * MB);   // 32 MiB, reuses Q/K/Vt/A (dead)
  float* F2  = (float*)(ws + 0 * MB);   // 16 MiB, reuses Xb (dead)

  cast_f32_to_bf16<<<M_TOK * HDIM / 1024, 256, 0, stream>>>(x, Xb);
  transpose_cast<<<dim3(HDIM / 32, HDIM / 32), 256, 0, stream>>>(Wq, WqT, HDIM, HDIM);
  transpose_cast<<<dim3(HDIM / 32, HDIM / 32), 256, 0, stream>>>(Wk, WkT, HDIM, HDIM);
  transpose_cast<<<dim3(HDIM / 32, HDIM / 32), 256, 0, stream>>>(Wv, WvT, HDIM, HDIM);
  transpose_cast<<<dim3(HDIM / 32, HDIM / 32), 256, 0, stream>>>(Wo, WoT, HDIM, HDIM);
  transpose_cast<<<dim3(FFDIM / 32, HDIM / 32), 256, 0, stream>>>(W1, W1T, HDIM, FFDIM);
  transpose_cast<<<dim3(HDIM / 32, FFDIM / 32), 256, 0, stream>>>(W2, W2T, FFDIM, HDIM);

  gemm_bt<0><<<dim3(HDIM / 128, M_TOK / 128), 256, 0, stream>>>(Xb, WqT, bq, Qb, M_TOK, HDIM, HDIM);
  gemm_bt<0><<<dim3(HDIM / 128, M_TOK / 128), 256, 0, stream>>>(Xb, WkT, bk, Kb, M_TOK, HDIM, HDIM);
  gemm_bt<3><<<dim3(HDIM / 128, M_TOK / 128), 256, 0, stream>>>(Xb, WvT, bv, Vtb, M_TOK, HDIM, HDIM);

  attn_kernel<<<dim3(SEQ / 128, BATCH * NHEAD), 256, 0, stream>>>(Qb, Kb, Vtb, am, Ab);

  gemm_bt<1><<<dim3(HDIM / 128, M_TOK / 128), 256, 0, stream>>>(Ab, WoT, bo, AWo, M_TOK, HDIM, HDIM);
  layernorm_k<1><<<M_TOK, 256, 0, stream>>>(AWo, ln1g, ln1b, L1);
  gemm_bt<2><<<dim3(FFDIM / 128, M_TOK / 128), 256, 0, stream>>>(L1, W1T, b1, F1, M_TOK, FFDIM, HDIM);
  gemm_bt<1><<<dim3(HDIM / 128, M_TOK / 128), 256, 0, stream>>>(F1, W2T, b2, F2, M_TOK, HDIM, FFDIM);
  layernorm_k<0><<<M_TOK, 256, 0, stream>>>(F2, ln2g, ln2b, (float*)d_out);
}

// Round 2
// 407.179 us; speedup vs baseline: 1.2584x; 1.2584x over previous
//
#include <hip/hip_runtime.h>
#include <hip/hip_bf16.h>
#include <math.h>

typedef __bf16 bf16;
typedef __attribute__((ext_vector_type(8))) __bf16 bf16x8;
typedef __attribute__((ext_vector_type(4))) __bf16 bf16x4;
typedef __attribute__((ext_vector_type(4))) float f32x4;

#define HDIM 1024
#define NHEAD 16
#define HD 64
#define FFDIM 4096
#define BATCH 2
#define SEQ 2048
#define M_TOK 4096  // BATCH*SEQ
#define PSTRIDE ((size_t)M_TOK * HDIM)  // f32 elements between split-K partials

static __device__ __forceinline__ void async_load16(const bf16* g, bf16* l) {
  __builtin_amdgcn_global_load_lds(
      (const __attribute__((address_space(1))) void*)g,
      (__attribute__((address_space(3))) void*)l, 16, 0, 0);
}

// ---------------------------------------------------------------- cast f32->bf16
__global__ __launch_bounds__(256)
void cast_f32_to_bf16(const float* __restrict__ in, bf16* __restrict__ out)
{
  const size_t i = ((size_t)blockIdx.x * 256 + threadIdx.x) * 4;
  f32x4 v = *(const f32x4*)(in + i);
  bf16x4 o;
#pragma unroll
  for (int j = 0; j < 4; ++j) o[j] = (bf16)v[j];
  *(bf16x4*)(out + i) = o;
}

// ------------------------------------------------- transpose+cast: in[R][C] f32 -> out[C][R] bf16
__global__ __launch_bounds__(256)
void transpose_cast(const float* __restrict__ in, bf16* __restrict__ out, int R, int C)
{
  __shared__ float tile[32][33];
  const int tx = threadIdx.x & 31, ty = threadIdx.x >> 5;
  const int c0 = blockIdx.x * 32, r0 = blockIdx.y * 32;
#pragma unroll
  for (int i = 0; i < 32; i += 8)
    tile[ty + i][tx] = in[(size_t)(r0 + ty + i) * C + c0 + tx];
  __syncthreads();
#pragma unroll
  for (int i = 0; i < 32; i += 8)
    out[(size_t)(c0 + ty + i) * R + r0 + tx] = (bf16)tile[tx][ty + i];
}

// 4 batched 1024x1024 transposes (Wq,Wk,Wv,Wo) -> contiguous dst (QKVT then WoT)
__global__ __launch_bounds__(256)
void transpose_cast4(const float* __restrict__ s0, const float* __restrict__ s1,
                     const float* __restrict__ s2, const float* __restrict__ s3,
                     bf16* __restrict__ dstBase)
{
  __shared__ float tile[32][33];
  const int z = blockIdx.z;
  const float* in = (z == 0) ? s0 : (z == 1) ? s1 : (z == 2) ? s2 : s3;
  bf16* out = dstBase + (size_t)z * HDIM * HDIM;
  const int tx = threadIdx.x & 31, ty = threadIdx.x >> 5;
  const int c0 = blockIdx.x * 32, r0 = blockIdx.y * 32;
#pragma unroll
  for (int i = 0; i < 32; i += 8)
    tile[ty + i][tx] = in[(size_t)(r0 + ty + i) * HDIM + c0 + tx];
  __syncthreads();
#pragma unroll
  for (int i = 0; i < 32; i += 8)
    out[(size_t)(c0 + ty + i) * HDIM + r0 + tx] = (bf16)tile[tx][ty + i];
}

// ---------------------------------------------------------------- GEMM  C = A @ Bt^T (+ bias)
// A[M][ldk] bf16, Bt[N][ldk] bf16. 128x128 tile, BK=64. blockIdx.z = split-K chunk.
// EPI: 1 = f32 partial (no bias, out + z*M*N), 2 = bias+gelu->bf16, 3 = QKV fused epilogue
template<int EPI>
__global__ __launch_bounds__(256)
void gemm_bt(const bf16* __restrict__ A, const bf16* __restrict__ Bt,
             const float* __restrict__ bias, void* __restrict__ Cout,
             int M, int N, int ldk, int kchunk)
{
  __shared__ __align__(16) bf16 As[128 * 64];
  __shared__ __align__(16) bf16 Bs[128 * 64];
  const int t = threadIdx.x;
  const int wave = t >> 6, lane = t & 63;
  const int lm = lane & 15, qd = lane >> 4;
  const int wm = (wave >> 1) * 64, wn = (wave & 1) * 64;
  const int bm = blockIdx.y * 128, bn = blockIdx.x * 128;
  const int kbeg = blockIdx.z * kchunk;

  f32x4 acc[4][4] = {};
  const int srow = t >> 3;
  const int schk = t & 7;

  for (int k0 = kbeg; k0 < kbeg + kchunk; k0 += 64) {
#pragma unroll
    for (int r = 0; r < 4; ++r) {
      const int row = r * 32 + srow;
      const int chunk = schk ^ (row & 7);
      async_load16(A + (size_t)(bm + row) * ldk + (k0 + chunk * 8),
                   (bf16*)((char*)As + r * 4096 + t * 16));
    }
#pragma unroll
    for (int r = 0; r < 4; ++r) {
      const int row = r * 32 + srow;
      const int chunk = schk ^ (row & 7);
      async_load16(Bt + (size_t)(bn + row) * ldk + (k0 + chunk * 8),
                   (bf16*)((char*)Bs + r * 4096 + t * 16));
    }
    __syncthreads();
#pragma unroll
    for (int ks = 0; ks < 2; ++ks) {
      bf16x8 av[4], bv[4];
#pragma unroll
      for (int mt = 0; mt < 4; ++mt) {
        const int row = wm + mt * 16 + lm;
        const int chunk = (ks * 4 + qd) ^ (row & 7);
        av[mt] = *(const bf16x8*)(As + row * 64 + chunk * 8);
      }
#pragma unroll
      for (int nt = 0; nt < 4; ++nt) {
        const int row = wn + nt * 16 + lm;
        const int chunk = (ks * 4 + qd) ^ (row & 7);
        bv[nt] = *(const bf16x8*)(Bs + row * 64 + chunk * 8);
      }
#pragma unroll
      for (int mt = 0; mt < 4; ++mt)
#pragma unroll
        for (int nt = 0; nt < 4; ++nt)
          acc[mt][nt] = __builtin_amdgcn_mfma_f32_16x16x32_bf16(av[mt], bv[nt], acc[mt][nt], 0, 0, 0);
    }
    __syncthreads();
  }

#pragma unroll
  for (int nt = 0; nt < 4; ++nt) {
    const int col = bn + wn + nt * 16 + lm;
    const float bs = (EPI == 1) ? 0.f : bias[col];
#pragma unroll
    for (int mt = 0; mt < 4; ++mt) {
#pragma unroll
      for (int r = 0; r < 4; ++r) {
        const int row = bm + wm + mt * 16 + qd * 4 + r;
        float v = acc[mt][nt][r] + bs;
        if (EPI == 1) {
          ((float*)Cout + (size_t)blockIdx.z * M * N)[(size_t)row * N + col] = v;
        } else if (EPI == 2) {
          float g = v * 0.5f * (1.0f + erff(v * 0.70710678118f));
          ((bf16*)Cout)[(size_t)row * N + col] = (bf16)g;
        } else {  // QKV fused: cols [0,1024)->Q std, [1024,2048)->K std, rest->Vt
          bf16* base = (bf16*)Cout;
          const int sect = col >> 10, c = col & 1023;
          if (sect < 2) {
            base[(size_t)sect * M_TOK * HDIM + (size_t)row * HDIM + c] = (bf16)v;
          } else {
            const int hh = c >> 6, dd = c & 63;
            const int bb = row >> 11, ss = row & 2047;
            base[(size_t)2 * M_TOK * HDIM +
                 (size_t)((bb * NHEAD + hh) * HD + dd) * SEQ + ss] = (bf16)v;
          }
        }
      }
    }
  }
}

// ---------------------------------------------------------------- flash attention (transposed)
// S^T = K @ Q^T  (softmax reductions in-lane), O^T = V^T @ P^T, exp2-domain.
// grid (SEQ/64, BATCH*NHEAD), 256 thr. Wave w: 16 q-rows. KV tile 64.
__global__ __launch_bounds__(256)
void attn_kernel(const bf16* __restrict__ Q, const bf16* __restrict__ Kg,
                 const bf16* __restrict__ Vt, const int* __restrict__ mask,
                 bf16* __restrict__ Aout)
{
  __shared__ __align__(16) bf16 Ks[64 * 64];   // [key][d], chunk-swizzled
  __shared__ __align__(16) bf16 Vs[64 * 64];   // [d][key], chunk-swizzled
  __shared__ __align__(16) bf16 Ps[4][16 * 64];// per-wave [q][key], chunk-swizzled
  __shared__ float madd[64];

  const int t = threadIdx.x;
  const int wave = t >> 6, lane = t & 63;
  const int lm = lane & 15, qd = lane >> 4;
  const int bh = blockIdx.y;
  const int b = bh >> 4, h = bh & 15;
  const int q0 = blockIdx.x * 64;
  const int qg = q0 + wave * 16 + lm;  // this lane's q row
  bf16* Psw = Ps[wave];

  // Q^T B-fragments (same lane layout as A): lane holds q=lm col, d = ks*32+qd*8..+8
  bf16x8 qf[2];
#pragma unroll
  for (int ks = 0; ks < 2; ++ks)
    qf[ks] = *(const bf16x8*)(Q + (size_t)(b * SEQ + qg) * HDIM + h * HD + ks * 32 + qd * 8);

  float m_run = -3.0e38f, l_run = 0.f;
  f32x4 oacc[4] = {};  // O^T: row d = nt*16+qd*4+r, col q = lm

  const int srow = t >> 3, schk = t & 7;
  const float C = 0.1803368801f;  // log2(e)/8  (exp2-domain, fp32 — no bf16 rounding)

  for (int kv0 = 0; kv0 < SEQ; kv0 += 64) {
#pragma unroll
    for (int r = 0; r < 2; ++r) {
      const int row = r * 32 + srow;
      const int g = schk ^ (row & 7);
      async_load16(Kg + (size_t)(b * SEQ + kv0 + row) * HDIM + h * HD + g * 8,
                   (bf16*)((char*)Ks + r * 4096 + t * 16));
      async_load16(Vt + (size_t)(bh * HD + row) * SEQ + kv0 + g * 8,
                   (bf16*)((char*)Vs + r * 4096 + t * 16));
    }
    if (t < 64) madd[t] = (mask[b * SEQ + kv0 + t] == 1) ? 0.f : -1.0e30f;
    __syncthreads();

    // S^T = K @ Q^T : A = K frag, B = Q^T frag
    f32x4 sacc[4] = {};
#pragma unroll
    for (int ks = 0; ks < 2; ++ks) {
#pragma unroll
      for (int nt = 0; nt < 4; ++nt) {
        const int row = nt * 16 + lm;
        const int c = (ks * 4 + qd) ^ (row & 7);
        bf16x8 kf = *(const bf16x8*)(Ks + row * 64 + c * 8);
        sacc[nt] = __builtin_amdgcn_mfma_f32_16x16x32_bf16(kf, qf[ks], sacc[nt], 0, 0, 0);
      }
    }

    // scale to log2-domain + mask; in-lane max over this lane's 16 keys
    float smax = -3.0e38f;
#pragma unroll
    for (int nt = 0; nt < 4; ++nt) {
      f32x4 ma = *(const f32x4*)(madd + nt * 16 + qd * 4);
#pragma unroll
      for (int r = 0; r < 4; ++r) {
        float s = fmaf(sacc[nt][r], C, ma[r]);
        sacc[nt][r] = s;
        smax = fmaxf(smax, s);
      }
    }
    smax = fmaxf(smax, __shfl_xor(smax, 16, 64));
    smax = fmaxf(smax, __shfl_xor(smax, 32, 64));
    const float mnew = fmaxf(m_run, smax);
    const float alpha = __builtin_amdgcn_exp2f(m_run - mnew);
    m_run = mnew;

    float lsum = 0.f;
#pragma unroll
    for (int nt = 0; nt < 4; ++nt)
#pragma unroll
      for (int r = 0; r < 4; ++r) {
        float pv = __builtin_amdgcn_exp2f(sacc[nt][r] - mnew);
        sacc[nt][r] = pv;
        lsum += pv;
      }
    lsum += __shfl_xor(lsum, 16, 64);
    lsum += __shfl_xor(lsum, 32, 64);
    l_run = fmaf(l_run, alpha, lsum);

#pragma unroll
    for (int nt = 0; nt < 4; ++nt) {
#pragma unroll
      for (int r = 0; r < 4; ++r) oacc[nt][r] *= alpha;
      bf16x4 pk;
#pragma unroll
      for (int r = 0; r < 4; ++r) pk[r] = (bf16)sacc[nt][r];
      // P^T pack: 4 consecutive keys -> one b64 write. 16B-chunk swizzle by q&7.
      *(bf16x4*)((char*)Psw + lm * 128 +
                 (((nt * 2 + (qd >> 1)) ^ (lm & 7)) * 16) + (qd & 1) * 8) = pk;
    }

    // O^T += V^T @ P^T
#pragma unroll
    for (int ks = 0; ks < 2; ++ks) {
      bf16x8 pf = *(const bf16x8*)((char*)Psw + lm * 128 + (((ks * 4 + qd) ^ (lm & 7)) * 16));
#pragma unroll
      for (int nt = 0; nt < 4; ++nt) {
        const int row = nt * 16 + lm;
        const int c = (ks * 4 + qd) ^ (row & 7);
        bf16x8 vf = *(const bf16x8*)(Vs + row * 64 + c * 8);
        oacc[nt] = __builtin_amdgcn_mfma_f32_16x16x32_bf16(vf, pf, oacc[nt], 0, 0, 0);
      }
    }
    __syncthreads();
  }

  // epilogue: normalize, transpose O^T -> O through per-wave LDS, coalesced store
  const float inv = 1.0f / l_run;
#pragma unroll
  for (int nt = 0; nt < 4; ++nt) {
    bf16x4 ok;
#pragma unroll
    for (int r = 0; r < 4; ++r) ok[r] = (bf16)(oacc[nt][r] * inv);
    *(bf16x4*)((char*)Psw + lm * 128 +
               (((nt * 2 + (qd >> 1)) ^ (lm & 7)) * 16) + (qd & 1) * 8) = ok;
  }
#pragma unroll
  for (int rr = 0; rr < 2; ++rr) {
    const int ql = rr * 8 + (lane >> 3);
    const int cl = lane & 7;
    bf16x8 v = *(const bf16x8*)((char*)Psw + ql * 128 + ((cl ^ (ql & 7)) * 16));
    *(bf16x8*)(Aout + (size_t)(b * SEQ + q0 + wave * 16 + ql) * HDIM + h * HD + cl * 8) = v;
  }
}

// ------------------------------------------- layernorm over H=1024, summing NP split-K partials + bias
template<int NP, int OUT_BF16>
__global__ __launch_bounds__(256)
void ln_sum(const float* __restrict__ p, const float* __restrict__ bias,
            const float* __restrict__ gamma, const float* __restrict__ beta,
            void* __restrict__ out)
{
  const int row = blockIdx.x;
  const int t = threadIdx.x;
  f32x4 v = *(const f32x4*)(p + (size_t)row * HDIM + t * 4);
#pragma unroll
  for (int np = 1; np < NP; ++np) {
    f32x4 u = *(const f32x4*)(p + np * PSTRIDE + (size_t)row * HDIM + t * 4);
#pragma unroll
    for (int j = 0; j < 4; ++j) v[j] += u[j];
  }
  f32x4 bv0 = *(const f32x4*)(bias + t * 4);
#pragma unroll
  for (int j = 0; j < 4; ++j) v[j] += bv0[j];

  float s = v[0] + v[1] + v[2] + v[3];
  float s2 = v[0] * v[0] + v[1] * v[1] + v[2] * v[2] + v[3] * v[3];
#pragma unroll
  for (int d = 1; d < 64; d <<= 1) { s += __shfl_xor(s, d, 64); s2 += __shfl_xor(s2, d, 64); }
  __shared__ float ss[4], ss2[4];
  const int wave = t >> 6, lane = t & 63;
  if (lane == 0) { ss[wave] = s; ss2[wave] = s2; }
  __syncthreads();
  s = ss[0] + ss[1] + ss[2] + ss[3];
  s2 = ss2[0] + ss2[1] + ss2[2] + ss2[3];
  const float mean = s * (1.0f / HDIM);
  const float var = s2 * (1.0f / HDIM) - mean * mean;
  const float rstd = rsqrtf(var + 1e-12f);
  f32x4 gv = *(const f32x4*)(gamma + t * 4);
  f32x4 bv = *(const f32x4*)(beta + t * 4);
  f32x4 y;
#pragma unroll
  for (int j = 0; j < 4; ++j) y[j] = gv[j] * (v[j] - mean) * rstd + bv[j];
  if (OUT_BF16) {
    bf16x4 o;
#pragma unroll
    for (int j = 0; j < 4; ++j) o[j] = (bf16)y[j];
    *(bf16x4*)((bf16*)out + (size_t)row * HDIM + t * 4) = o;
  } else {
    *(f32x4*)((float*)out + (size_t)row * HDIM + t * 4) = y;
  }
}

// ---------------------------------------------------------------- launch
extern "C" void kernel_launch(void* const* d_in, const int* in_sizes, int n_in,
                              void* d_out, int out_size, void* d_ws, size_t ws_size,
                              hipStream_t stream)
{
  const float* x    = (const float*)d_in[0];
  const int*   am   = (const int*)d_in[1];
  const float* Wq   = (const float*)d_in[2];
  const float* bq   = (const float*)d_in[3];
  const float* Wk   = (const float*)d_in[4];
  const float* bk   = (const float*)d_in[5];
  const float* Wv   = (const float*)d_in[6];
  const float* bv   = (const float*)d_in[7];
  const float* Wo   = (const float*)d_in[8];
  const float* bo   = (const float*)d_in[9];
  const float* ln1g = (const float*)d_in[10];
  const float* ln1b = (const float*)d_in[11];
  const float* W1   = (const float*)d_in[12];
  const float* b1   = (const float*)d_in[13];
  const float* W2   = (const float*)d_in[14];
  const float* b2   = (const float*)d_in[15];
  const float* ln2g = (const float*)d_in[16];
  const float* ln2b = (const float*)d_in[17];

  char* ws = (char*)d_ws;
  const size_t MB = 1ull << 20;
  // liveness-packed map (peak 80 MiB):
  bf16*  W1T  = (bf16*)(ws + 0 * MB);    // 8 MiB   tr -> FFN1
  bf16*  W2T  = (bf16*)(ws + 8 * MB);    // 8 MiB   tr -> FFN2
  bf16*  Xb   = (bf16*)(ws + 16 * MB);   // 8 MiB   cast -> QKV
  bf16*  QKVT = (bf16*)(ws + 24 * MB);   // 6 MiB   (+WoT contiguous at +6MiB)
  bf16*  WoT  = (bf16*)(ws + 30 * MB);   // 2 MiB   tr -> Wo gemm
  float* bqkv = (float*)(ws + 32 * MB);  // 12 KiB
  bf16*  Qb   = (bf16*)(ws + 33 * MB);   // 8+8+8 MiB: Q,K std then Vt (contiguous for QKV epi)
  bf16*  Kb   = (bf16*)(ws + 41 * MB);
  bf16*  Vtb  = (bf16*)(ws + 49 * MB);
  bf16*  Ab   = (bf16*)(ws + 16 * MB);   // reuse Xb (dead after QKV): attn -> Wo
  float* Pw   = (float*)(ws + 33 * MB);  // Wo partials z0@33,z1@49 (reuse Q/K/Vt, dead)
  bf16*  L1   = (bf16*)(ws + 65 * MB);   // 8 MiB   LN1 -> FFN1
  bf16*  F1   = (bf16*)(ws + 16 * MB);   // 32 MiB  FFN1 -> FFN2 (16-48, all dead)
  float* Pf   = (float*)(ws + 48 * MB);  // FFN2 partials z0@48,z1@64 (P1/L1 dead)

  cast_f32_to_bf16<<<M_TOK * HDIM / 1024, 256, 0, stream>>>(x, Xb);
  transpose_cast4<<<dim3(32, 32, 4), 256, 0, stream>>>(Wq, Wk, Wv, Wo, QKVT);
  transpose_cast<<<dim3(FFDIM / 32, HDIM / 32), 256, 0, stream>>>(W1, W1T, HDIM, FFDIM);
  transpose_cast<<<dim3(HDIM / 32, FFDIM / 32), 256, 0, stream>>>(W2, W2T, FFDIM, HDIM);
  hipMemcpyAsync(bqkv,        bq, HDIM * 4, hipMemcpyDeviceToDevice, stream);
  hipMemcpyAsync(bqkv + 1024, bk, HDIM * 4, hipMemcpyDeviceToDevice, stream);
  hipMemcpyAsync(bqkv + 2048, bv, HDIM * 4, hipMemcpyDeviceToDevice, stream);

  // fused QKV: N=3072, 768 blocks
  gemm_bt<3><<<dim3(3072 / 128, M_TOK / 128, 1), 256, 0, stream>>>(
      Xb, QKVT, bqkv, Qb, M_TOK, 3072, HDIM, HDIM);

  attn_kernel<<<dim3(SEQ / 64, BATCH * NHEAD), 256, 0, stream>>>(Qb, Kb, Vtb, am, Ab);

  // Wo: split-K z=2 (Kchunk 512) -> f32 partials; LN1 sums + bias
  gemm_bt<1><<<dim3(HDIM / 128, M_TOK / 128, 2), 256, 0, stream>>>(
      Ab, WoT, nullptr, Pw, M_TOK, HDIM, HDIM, 512);
  ln_sum<2, 1><<<M_TOK, 256, 0, stream>>>(Pw, bo, ln1g, ln1b, L1);

  gemm_bt<2><<<dim3(FFDIM / 128, M_TOK / 128, 1), 256, 0, stream>>>(
      L1, W1T, b1, F1, M_TOK, FFDIM, HDIM, HDIM);

  // FFN2: split-K z=2 (Kchunk 2048) -> f32 partials; LN2 sums + bias -> f32 out
  gemm_bt<1><<<dim3(HDIM / 128, M_TOK / 128, 2), 256, 0, stream>>>(
      F1, W2T, nullptr, Pf, M_TOK, HDIM, FFDIM, 2048);
  ln_sum<2, 0><<<M_TOK, 256, 0, stream>>>(Pf, b2, ln2g, ln2b, (float*)d_out);
}

// Round 3
// 395.168 us; speedup vs baseline: 1.2966x; 1.0304x over previous
//
#include <hip/hip_runtime.h>
#include <hip/hip_bf16.h>
#include <math.h>

typedef __bf16 bf16;
typedef __attribute__((ext_vector_type(8))) __bf16 bf16x8;
typedef __attribute__((ext_vector_type(4))) __bf16 bf16x4;
typedef __attribute__((ext_vector_type(4))) float f32x4;

#define HDIM 1024
#define NHEAD 16
#define HD 64
#define FFDIM 4096
#define BATCH 2
#define SEQ 2048
#define M_TOK 4096  // BATCH*SEQ
#define PSTRIDE ((size_t)M_TOK * HDIM)  // f32 elements between split-K partials

static __device__ __forceinline__ void async_load16(const bf16* g, bf16* l) {
  __builtin_amdgcn_global_load_lds(
      (const __attribute__((address_space(1))) void*)g,
      (__attribute__((address_space(3))) void*)l, 16, 0, 0);
}

// ---------------------------------------------------------------- cast f32->bf16
__global__ __launch_bounds__(256)
void cast_f32_to_bf16(const float* __restrict__ in, bf16* __restrict__ out)
{
  const size_t i = ((size_t)blockIdx.x * 256 + threadIdx.x) * 4;
  f32x4 v = *(const f32x4*)(in + i);
  bf16x4 o;
#pragma unroll
  for (int j = 0; j < 4; ++j) o[j] = (bf16)v[j];
  *(bf16x4*)(out + i) = o;
}

// ------------------------------------------------- transpose+cast: in[R][C] f32 -> out[C][R] bf16
__global__ __launch_bounds__(256)
void transpose_cast(const float* __restrict__ in, bf16* __restrict__ out, int R, int C)
{
  __shared__ float tile[32][33];
  const int tx = threadIdx.x & 31, ty = threadIdx.x >> 5;
  const int c0 = blockIdx.x * 32, r0 = blockIdx.y * 32;
#pragma unroll
  for (int i = 0; i < 32; i += 8)
    tile[ty + i][tx] = in[(size_t)(r0 + ty + i) * C + c0 + tx];
  __syncthreads();
#pragma unroll
  for (int i = 0; i < 32; i += 8)
    out[(size_t)(c0 + ty + i) * R + r0 + tx] = (bf16)tile[tx][ty + i];
}

// 4 batched 1024x1024 transposes (Wq,Wk,Wv,Wo) -> contiguous dst (QKVT then WoT)
__global__ __launch_bounds__(256)
void transpose_cast4(const float* __restrict__ s0, const float* __restrict__ s1,
                     const float* __restrict__ s2, const float* __restrict__ s3,
                     bf16* __restrict__ dstBase)
{
  __shared__ float tile[32][33];
  const int z = blockIdx.z;
  const float* in = (z == 0) ? s0 : (z == 1) ? s1 : (z == 2) ? s2 : s3;
  bf16* out = dstBase + (size_t)z * HDIM * HDIM;
  const int tx = threadIdx.x & 31, ty = threadIdx.x >> 5;
  const int c0 = blockIdx.x * 32, r0 = blockIdx.y * 32;
#pragma unroll
  for (int i = 0; i < 32; i += 8)
    tile[ty + i][tx] = in[(size_t)(r0 + ty + i) * HDIM + c0 + tx];
  __syncthreads();
#pragma unroll
  for (int i = 0; i < 32; i += 8)
    out[(size_t)(c0 + ty + i) * HDIM + r0 + tx] = (bf16)tile[tx][ty + i];
}

// ---------------------------------------------------------------- GEMM  C = A @ Bt^T (+ bias)
// A[M][ldk] bf16, Bt[N][ldk] bf16. 128x128 tile, BK=64. blockIdx.z = split-K chunk.
// EPI: 1 = f32 partial (no bias, out + z*M*N), 2 = bias+gelu->bf16, 3 = QKV fused epilogue
template<int EPI>
__global__ __launch_bounds__(256)
void gemm_bt(const bf16* __restrict__ A, const bf16* __restrict__ Bt,
             const float* __restrict__ bias, void* __restrict__ Cout,
             int M, int N, int ldk, int kchunk)
{
  __shared__ __align__(16) bf16 As[128 * 64];
  __shared__ __align__(16) bf16 Bs[128 * 64];
  const int t = threadIdx.x;
  const int wave = t >> 6, lane = t & 63;
  const int lm = lane & 15, qd = lane >> 4;
  const int wm = (wave >> 1) * 64, wn = (wave & 1) * 64;
  const int bm = blockIdx.y * 128, bn = blockIdx.x * 128;
  const int kbeg = blockIdx.z * kchunk;

  f32x4 acc[4][4] = {};
  const int srow = t >> 3;
  const int schk = t & 7;

  for (int k0 = kbeg; k0 < kbeg + kchunk; k0 += 64) {
#pragma unroll
    for (int r = 0; r < 4; ++r) {
      const int row = r * 32 + srow;
      const int chunk = schk ^ (row & 7);
      async_load16(A + (size_t)(bm + row) * ldk + (k0 + chunk * 8),
                   (bf16*)((char*)As + r * 4096 + t * 16));
    }
#pragma unroll
    for (int r = 0; r < 4; ++r) {
      const int row = r * 32 + srow;
      const int chunk = schk ^ (row & 7);
      async_load16(Bt + (size_t)(bn + row) * ldk + (k0 + chunk * 8),
                   (bf16*)((char*)Bs + r * 4096 + t * 16));
    }
    __syncthreads();
#pragma unroll
    for (int ks = 0; ks < 2; ++ks) {
      bf16x8 av[4], bv[4];
#pragma unroll
      for (int mt = 0; mt < 4; ++mt) {
        const int row = wm + mt * 16 + lm;
        const int chunk = (ks * 4 + qd) ^ (row & 7);
        av[mt] = *(const bf16x8*)(As + row * 64 + chunk * 8);
      }
#pragma unroll
      for (int nt = 0; nt < 4; ++nt) {
        const int row = wn + nt * 16 + lm;
        const int chunk = (ks * 4 + qd) ^ (row & 7);
        bv[nt] = *(const bf16x8*)(Bs + row * 64 + chunk * 8);
      }
#pragma unroll
      for (int mt = 0; mt < 4; ++mt)
#pragma unroll
        for (int nt = 0; nt < 4; ++nt)
          acc[mt][nt] = __builtin_amdgcn_mfma_f32_16x16x32_bf16(av[mt], bv[nt], acc[mt][nt], 0, 0, 0);
    }
    __syncthreads();
  }

#pragma unroll
  for (int nt = 0; nt < 4; ++nt) {
    const int col = bn + wn + nt * 16 + lm;
    const float bs = (EPI == 1) ? 0.f : bias[col];
#pragma unroll
    for (int mt = 0; mt < 4; ++mt) {
#pragma unroll
      for (int r = 0; r < 4; ++r) {
        const int row = bm + wm + mt * 16 + qd * 4 + r;
        float v = acc[mt][nt][r] + bs;
        if (EPI == 1) {
          ((float*)Cout + (size_t)blockIdx.z * M * N)[(size_t)row * N + col] = v;
        } else if (EPI == 2) {
          float g = v * 0.5f * (1.0f + erff(v * 0.70710678118f));
          ((bf16*)Cout)[(size_t)row * N + col] = (bf16)g;
        } else {  // QKV fused: cols [0,1024)->Q std, [1024,2048)->K std, rest->Vt
          bf16* base = (bf16*)Cout;
          const int sect = col >> 10, c = col & 1023;
          if (sect < 2) {
            base[(size_t)sect * M_TOK * HDIM + (size_t)row * HDIM + c] = (bf16)v;
          } else {
            const int hh = c >> 6, dd = c & 63;
            const int bb = row >> 11, ss = row & 2047;
            base[(size_t)2 * M_TOK * HDIM +
                 (size_t)((bb * NHEAD + hh) * HD + dd) * SEQ + ss] = (bf16)v;
          }
        }
      }
    }
  }
}

// ---------------------------------------------------------------- flash attention (transposed, no-max)
// S^T = K @ Q^T, O^T = V^T @ P^T, exp2-domain WITHOUT running max:
// scores are bounded (|s|*log2e/8 << 127), so exp2 cannot overflow; softmax
// denominator accumulates in-lane across tiles, reduced once at the end.
// grid (SEQ/64, BATCH*NHEAD), 256 thr. Wave w: 16 q-rows. KV tile 64.
__global__ __launch_bounds__(256)
void attn_kernel(const bf16* __restrict__ Q, const bf16* __restrict__ Kg,
                 const bf16* __restrict__ Vt, const int* __restrict__ mask,
                 bf16* __restrict__ Aout)
{
  __shared__ __align__(16) bf16 Ks[64 * 64];   // [key][d], chunk-swizzled
  __shared__ __align__(16) bf16 Vs[64 * 64];   // [d][key], chunk-swizzled
  __shared__ __align__(16) bf16 Ps[4][16 * 64];// per-wave [q][key], chunk-swizzled
  __shared__ float madd[64];

  const int t = threadIdx.x;
  const int wave = t >> 6, lane = t & 63;
  const int lm = lane & 15, qd = lane >> 4;
  const int bh = blockIdx.y;
  const int b = bh >> 4, h = bh & 15;
  const int q0 = blockIdx.x * 64;
  const int qg = q0 + wave * 16 + lm;  // this lane's q column (of S^T)
  bf16* Psw = Ps[wave];

  // Q^T B-fragments: lane holds q=lm col, d = ks*32+qd*8..+8
  bf16x8 qf[2];
#pragma unroll
  for (int ks = 0; ks < 2; ++ks)
    qf[ks] = *(const bf16x8*)(Q + (size_t)(b * SEQ + qg) * HDIM + h * HD + ks * 32 + qd * 8);

  float l_lane = 0.f;      // in-lane partial denominator (this lane's 16 keys/tile)
  f32x4 oacc[4] = {};      // O^T: row d = nt*16+qd*4+r, col q = lm

  const int srow = t >> 3, schk = t & 7;
  const float C = 0.1803368801f;  // log2(e)/8

  for (int kv0 = 0; kv0 < SEQ; kv0 += 64) {
#pragma unroll
    for (int r = 0; r < 2; ++r) {
      const int row = r * 32 + srow;
      const int g = schk ^ (row & 7);
      async_load16(Kg + (size_t)(b * SEQ + kv0 + row) * HDIM + h * HD + g * 8,
                   (bf16*)((char*)Ks + r * 4096 + t * 16));
      async_load16(Vt + (size_t)(bh * HD + row) * SEQ + kv0 + g * 8,
                   (bf16*)((char*)Vs + r * 4096 + t * 16));
    }
    if (t < 64) madd[t] = (mask[b * SEQ + kv0 + t] == 1) ? 0.f : -1.0e30f;
    __syncthreads();

    // S^T = K @ Q^T : A = K frag, B = Q^T frag
    f32x4 sacc[4] = {};
#pragma unroll
    for (int ks = 0; ks < 2; ++ks) {
#pragma unroll
      for (int nt = 0; nt < 4; ++nt) {
        const int row = nt * 16 + lm;
        const int c = (ks * 4 + qd) ^ (row & 7);
        bf16x8 kf = *(const bf16x8*)(Ks + row * 64 + c * 8);
        sacc[nt] = __builtin_amdgcn_mfma_f32_16x16x32_bf16(kf, qf[ks], sacc[nt], 0, 0, 0);
      }
    }

    // p = exp2(s*C + mask); accumulate denominator in-lane; pack P^T to LDS
#pragma unroll
    for (int nt = 0; nt < 4; ++nt) {
      f32x4 ma = *(const f32x4*)(madd + nt * 16 + qd * 4);
      bf16x4 pk;
#pragma unroll
      for (int r = 0; r < 4; ++r) {
        const float pv = __builtin_amdgcn_exp2f(fmaf(sacc[nt][r], C, ma[r]));
        l_lane += pv;
        pk[r] = (bf16)pv;
      }
      // P^T pack: 4 consecutive keys -> one b64 write. 16B-chunk swizzle by q&7.
      *(bf16x4*)((char*)Psw + lm * 128 +
                 (((nt * 2 + (qd >> 1)) ^ (lm & 7)) * 16) + (qd & 1) * 8) = pk;
    }

    // O^T += V^T @ P^T
#pragma unroll
    for (int ks = 0; ks < 2; ++ks) {
      bf16x8 pf = *(const bf16x8*)((char*)Psw + lm * 128 + (((ks * 4 + qd) ^ (lm & 7)) * 16));
#pragma unroll
      for (int nt = 0; nt < 4; ++nt) {
        const int row = nt * 16 + lm;
        const int c = (ks * 4 + qd) ^ (row & 7);
        bf16x8 vf = *(const bf16x8*)(Vs + row * 64 + c * 8);
        oacc[nt] = __builtin_amdgcn_mfma_f32_16x16x32_bf16(vf, pf, oacc[nt], 0, 0, 0);
      }
    }
    __syncthreads();
  }

  // denominator: sum the 4 qd-lane partials per q column, once
  float l = l_lane;
  l += __shfl_xor(l, 16, 64);
  l += __shfl_xor(l, 32, 64);
  const float inv = 1.0f / l;

  // epilogue: normalize, transpose O^T -> O through per-wave LDS, coalesced store
#pragma unroll
  for (int nt = 0; nt < 4; ++nt) {
    bf16x4 ok;
#pragma unroll
    for (int r = 0; r < 4; ++r) ok[r] = (bf16)(oacc[nt][r] * inv);
    *(bf16x4*)((char*)Psw + lm * 128 +
               (((nt * 2 + (qd >> 1)) ^ (lm & 7)) * 16) + (qd & 1) * 8) = ok;
  }
#pragma unroll
  for (int rr = 0; rr < 2; ++rr) {
    const int ql = rr * 8 + (lane >> 3);
    const int cl = lane & 7;
    bf16x8 v = *(const bf16x8*)((char*)Psw + ql * 128 + ((cl ^ (ql & 7)) * 16));
    *(bf16x8*)(Aout + (size_t)(b * SEQ + q0 + wave * 16 + ql) * HDIM + h * HD + cl * 8) = v;
  }
}

// ------------------------------------------- layernorm over H=1024, summing NP split-K partials + bias
template<int NP, int OUT_BF16>
__global__ __launch_bounds__(256)
void ln_sum(const float* __restrict__ p, const float* __restrict__ bias,
            const float* __restrict__ gamma, const float* __restrict__ beta,
            void* __restrict__ out)
{
  const int row = blockIdx.x;
  const int t = threadIdx.x;
  f32x4 v = *(const f32x4*)(p + (size_t)row * HDIM + t * 4);
#pragma unroll
  for (int np = 1; np < NP; ++np) {
    f32x4 u = *(const f32x4*)(p + np * PSTRIDE + (size_t)row * HDIM + t * 4);
#pragma unroll
    for (int j = 0; j < 4; ++j) v[j] += u[j];
  }
  f32x4 bv0 = *(const f32x4*)(bias + t * 4);
#pragma unroll
  for (int j = 0; j < 4; ++j) v[j] += bv0[j];

  float s = v[0] + v[1] + v[2] + v[3];
  float s2 = v[0] * v[0] + v[1] * v[1] + v[2] * v[2] + v[3] * v[3];
#pragma unroll
  for (int d = 1; d < 64; d <<= 1) { s += __shfl_xor(s, d, 64); s2 += __shfl_xor(s2, d, 64); }
  __shared__ float ss[4], ss2[4];
  const int wave = t >> 6, lane = t & 63;
  if (lane == 0) { ss[wave] = s; ss2[wave] = s2; }
  __syncthreads();
  s = ss[0] + ss[1] + ss[2] + ss[3];
  s2 = ss2[0] + ss2[1] + ss2[2] + ss2[3];
  const float mean = s * (1.0f / HDIM);
  const float var = s2 * (1.0f / HDIM) - mean * mean;
  const float rstd = rsqrtf(var + 1e-12f);
  f32x4 gv = *(const f32x4*)(gamma + t * 4);
  f32x4 bv = *(const f32x4*)(beta + t * 4);
  f32x4 y;
#pragma unroll
  for (int j = 0; j < 4; ++j) y[j] = gv[j] * (v[j] - mean) * rstd + bv[j];
  if (OUT_BF16) {
    bf16x4 o;
#pragma unroll
    for (int j = 0; j < 4; ++j) o[j] = (bf16)y[j];
    *(bf16x4*)((bf16*)out + (size_t)row * HDIM + t * 4) = o;
  } else {
    *(f32x4*)((float*)out + (size_t)row * HDIM + t * 4) = y;
  }
}

// ---------------------------------------------------------------- launch
extern "C" void kernel_launch(void* const* d_in, const int* in_sizes, int n_in,
                              void* d_out, int out_size, void* d_ws, size_t ws_size,
                              hipStream_t stream)
{
  const float* x    = (const float*)d_in[0];
  const int*   am   = (const int*)d_in[1];
  const float* Wq   = (const float*)d_in[2];
  const float* bq   = (const float*)d_in[3];
  const float* Wk   = (const float*)d_in[4];
  const float* bk   = (const float*)d_in[5];
  const float* Wv   = (const float*)d_in[6];
  const float* bv   = (const float*)d_in[7];
  const float* Wo   = (const float*)d_in[8];
  const float* bo   = (const float*)d_in[9];
  const float* ln1g = (const float*)d_in[10];
  const float* ln1b = (const float*)d_in[11];
  const float* W1   = (const float*)d_in[12];
  const float* b1   = (const float*)d_in[13];
  const float* W2   = (const float*)d_in[14];
  const float* b2   = (const float*)d_in[15];
  const float* ln2g = (const float*)d_in[16];
  const float* ln2b = (const float*)d_in[17];

  char* ws = (char*)d_ws;
  const size_t MB = 1ull << 20;
  bf16*  W1T  = (bf16*)(ws + 0 * MB);    // 8 MiB   tr -> FFN1
  bf16*  W2T  = (bf16*)(ws + 8 * MB);    // 8 MiB   tr -> FFN2
  bf16*  Xb   = (bf16*)(ws + 16 * MB);   // 8 MiB   cast -> QKV
  bf16*  QKVT = (bf16*)(ws + 24 * MB);   // 6 MiB   (+WoT contiguous)
  bf16*  WoT  = (bf16*)(ws + 30 * MB);   // 2 MiB   tr -> Wo gemm
  float* bqkv = (float*)(ws + 32 * MB);  // 12 KiB
  bf16*  Qb   = (bf16*)(ws + 33 * MB);   // Q,K std then Vt (contiguous for QKV epi)
  bf16*  Kb   = (bf16*)(ws + 41 * MB);
  bf16*  Vtb  = (bf16*)(ws + 49 * MB);
  bf16*  Ab   = (bf16*)(ws + 16 * MB);   // reuse Xb (dead after QKV)
  float* Pw   = (float*)(ws + 33 * MB);  // Wo partials (reuse Q/K/Vt, dead)
  bf16*  L1   = (bf16*)(ws + 65 * MB);   // 8 MiB   LN1 -> FFN1
  bf16*  F1   = (bf16*)(ws + 16 * MB);   // 32 MiB  FFN1 -> FFN2
  float* Pf   = (float*)(ws + 48 * MB);  // FFN2 partials

  cast_f32_to_bf16<<<M_TOK * HDIM / 1024, 256, 0, stream>>>(x, Xb);
  transpose_cast4<<<dim3(32, 32, 4), 256, 0, stream>>>(Wq, Wk, Wv, Wo, QKVT);
  transpose_cast<<<dim3(FFDIM / 32, HDIM / 32), 256, 0, stream>>>(W1, W1T, HDIM, FFDIM);
  transpose_cast<<<dim3(HDIM / 32, FFDIM / 32), 256, 0, stream>>>(W2, W2T, FFDIM, HDIM);
  hipMemcpyAsync(bqkv,        bq, HDIM * 4, hipMemcpyDeviceToDevice, stream);
  hipMemcpyAsync(bqkv + 1024, bk, HDIM * 4, hipMemcpyDeviceToDevice, stream);
  hipMemcpyAsync(bqkv + 2048, bv, HDIM * 4, hipMemcpyDeviceToDevice, stream);

  gemm_bt<3><<<dim3(3072 / 128, M_TOK / 128, 1), 256, 0, stream>>>(
      Xb, QKVT, bqkv, Qb, M_TOK, 3072, HDIM, HDIM);

  attn_kernel<<<dim3(SEQ / 64, BATCH * NHEAD), 256, 0, stream>>>(Qb, Kb, Vtb, am, Ab);

  gemm_bt<1><<<dim3(HDIM / 128, M_TOK / 128, 2), 256, 0, stream>>>(
      Ab, WoT, nullptr, Pw, M_TOK, HDIM, HDIM, 512);
  ln_sum<2, 1><<<M_TOK, 256, 0, stream>>>(Pw, bo, ln1g, ln1b, L1);

  gemm_bt<2><<<dim3(FFDIM / 128, M_TOK / 128, 1), 256, 0, stream>>>(
      L1, W1T, b1, F1, M_TOK, FFDIM, HDIM, HDIM);

  gemm_bt<1><<<dim3(HDIM / 128, M_TOK / 128, 2), 256, 0, stream>>>(
      F1, W2T, nullptr, Pf, M_TOK, HDIM, FFDIM, 2048);
  ln_sum<2, 0><<<M_TOK, 256, 0, stream>>>(Pf, b2, ln2g, ln2b, (float*)d_out);
}

// Round 4
// 385.338 us; speedup vs baseline: 1.3297x; 1.0255x over previous
//
#include <hip/hip_runtime.h>
#include <hip/hip_bf16.h>
#include <math.h>

typedef __bf16 bf16;
typedef __attribute__((ext_vector_type(8))) __bf16 bf16x8;
typedef __attribute__((ext_vector_type(4))) __bf16 bf16x4;
typedef __attribute__((ext_vector_type(4))) float f32x4;

#define HDIM 1024
#define NHEAD 16
#define HD 64
#define FFDIM 4096
#define BATCH 2
#define SEQ 2048
#define M_TOK 4096  // BATCH*SEQ
#define PSTRIDE ((size_t)M_TOK * HDIM)  // f32 elements between split-K partials (16 MiB)

static __device__ __forceinline__ void async_load16(const bf16* g, bf16* l) {
  __builtin_amdgcn_global_load_lds(
      (const __attribute__((address_space(1))) void*)g,
      (__attribute__((address_space(3))) void*)l, 16, 0, 0);
}

// ---------------------------------------------------------------- prep: all transposes + x cast
// z 0..3: Wq/Wk/Wv/Wo 1024x1024 -> QKVT + z*1M        (src ld 1024, dst ld 1024)
// z 4..7: W1 col-chunk c -> W1T + c*1M                (src ld 4096, dst ld 1024)
// z 8..11: W2 row-chunk c -> W2T + c*1024             (src ld 1024, dst ld 4096)
// z 12:   cast x (4M f32) -> Xb bf16
__global__ __launch_bounds__(256)
void prep_kernel(const float* __restrict__ x,
                 const float* __restrict__ Wq, const float* __restrict__ Wk,
                 const float* __restrict__ Wv, const float* __restrict__ Wo,
                 const float* __restrict__ W1, const float* __restrict__ W2,
                 bf16* __restrict__ Xb, bf16* __restrict__ QKVT,
                 bf16* __restrict__ W1T, bf16* __restrict__ W2T)
{
  const int z = blockIdx.z;
  const int t = threadIdx.x;
  if (z == 12) {
    const size_t base = ((size_t)(blockIdx.y * 32 + blockIdx.x)) * 4096;
#pragma unroll
    for (int j = 0; j < 4; ++j) {
      const size_t i = base + j * 1024 + t * 4;
      f32x4 v = *(const f32x4*)(x + i);
      bf16x4 o;
#pragma unroll
      for (int k = 0; k < 4; ++k) o[k] = (bf16)v[k];
      *(bf16x4*)(Xb + i) = o;
    }
    return;
  }
  const float* ps; bf16* pd; int sld, dld;
  if (z < 4) {
    ps = (z == 0) ? Wq : (z == 1) ? Wk : (z == 2) ? Wv : Wo;
    pd = QKVT + (size_t)z * HDIM * HDIM; sld = 1024; dld = 1024;
  } else if (z < 8) {
    const int c = z - 4;
    ps = W1 + c * 1024; sld = 4096;
    pd = W1T + (size_t)c * 1024 * 1024; dld = 1024;
  } else {
    const int c = z - 8;
    ps = W2 + (size_t)c * 1024 * 1024; sld = 1024;
    pd = W2T + c * 1024; dld = 4096;
  }
  __shared__ float tile[32][33];
  const int tx = t & 31, ty = t >> 5;
  const int c0 = blockIdx.x * 32, r0 = blockIdx.y * 32;
#pragma unroll
  for (int i = 0; i < 32; i += 8)
    tile[ty + i][tx] = ps[(size_t)(r0 + ty + i) * sld + c0 + tx];
  __syncthreads();
#pragma unroll
  for (int i = 0; i < 32; i += 8)
    pd[(size_t)(c0 + ty + i) * dld + r0 + tx] = (bf16)tile[tx][ty + i];
}

// ---------------------------------------------------------------- GEMM  C = A @ Bt^T (+ bias)
// A[M][ldk] bf16, Bt[N][ldk] bf16. 128x128 tile, BK=64. blockIdx.z = split-K chunk.
// EPI: 1 = f32 partial (no bias, out + z*M*N), 2 = bias+gelu->bf16 (A&S erf),
//      3 = QKV fused epilogue (bias selected from b0/b1/b2 by col>>10)
template<int EPI>
__global__ __launch_bounds__(256)
void gemm_bt(const bf16* __restrict__ A, const bf16* __restrict__ Bt,
             const float* __restrict__ b0, const float* __restrict__ b1p,
             const float* __restrict__ b2p, void* __restrict__ Cout,
             int M, int N, int ldk, int kchunk)
{
  __shared__ __align__(16) bf16 As[128 * 64];
  __shared__ __align__(16) bf16 Bs[128 * 64];
  const int t = threadIdx.x;
  const int wave = t >> 6, lane = t & 63;
  const int lm = lane & 15, qd = lane >> 4;
  const int wm = (wave >> 1) * 64, wn = (wave & 1) * 64;
  const int bm = blockIdx.y * 128, bn = blockIdx.x * 128;
  const int kbeg = blockIdx.z * kchunk;

  f32x4 acc[4][4] = {};
  const int srow = t >> 3;
  const int schk = t & 7;

  for (int k0 = kbeg; k0 < kbeg + kchunk; k0 += 64) {
#pragma unroll
    for (int r = 0; r < 4; ++r) {
      const int row = r * 32 + srow;
      const int chunk = schk ^ (row & 7);
      async_load16(A + (size_t)(bm + row) * ldk + (k0 + chunk * 8),
                   (bf16*)((char*)As + r * 4096 + t * 16));
    }
#pragma unroll
    for (int r = 0; r < 4; ++r) {
      const int row = r * 32 + srow;
      const int chunk = schk ^ (row & 7);
      async_load16(Bt + (size_t)(bn + row) * ldk + (k0 + chunk * 8),
                   (bf16*)((char*)Bs + r * 4096 + t * 16));
    }
    __syncthreads();
#pragma unroll
    for (int ks = 0; ks < 2; ++ks) {
      bf16x8 av[4], bv[4];
#pragma unroll
      for (int mt = 0; mt < 4; ++mt) {
        const int row = wm + mt * 16 + lm;
        const int chunk = (ks * 4 + qd) ^ (row & 7);
        av[mt] = *(const bf16x8*)(As + row * 64 + chunk * 8);
      }
#pragma unroll
      for (int nt = 0; nt < 4; ++nt) {
        const int row = wn + nt * 16 + lm;
        const int chunk = (ks * 4 + qd) ^ (row & 7);
        bv[nt] = *(const bf16x8*)(Bs + row * 64 + chunk * 8);
      }
#pragma unroll
      for (int mt = 0; mt < 4; ++mt)
#pragma unroll
        for (int nt = 0; nt < 4; ++nt)
          acc[mt][nt] = __builtin_amdgcn_mfma_f32_16x16x32_bf16(av[mt], bv[nt], acc[mt][nt], 0, 0, 0);
    }
    __syncthreads();
  }

#pragma unroll
  for (int nt = 0; nt < 4; ++nt) {
    const int col = bn + wn + nt * 16 + lm;
    float bs = 0.f;
    if (EPI == 2) bs = b0[col];
    if (EPI == 3) {
      const int sect = col >> 10, c = col & 1023;
      bs = (sect == 0) ? b0[c] : (sect == 1) ? b1p[c] : b2p[c];
    }
#pragma unroll
    for (int mt = 0; mt < 4; ++mt) {
#pragma unroll
      for (int r = 0; r < 4; ++r) {
        const int row = bm + wm + mt * 16 + qd * 4 + r;
        float v = acc[mt][nt][r] + bs;
        if (EPI == 1) {
          ((float*)Cout + (size_t)blockIdx.z * M * N)[(size_t)row * N + col] = v;
        } else if (EPI == 2) {
          // gelu via A&S 7.1.26 erf (|err| < 1.5e-7), branch-free
          const float z = v * 0.70710678118f;
          const float az = fabsf(z);
          const float tt = __builtin_amdgcn_rcpf(fmaf(az, 0.3275911f, 1.0f));
          const float poly = tt * fmaf(tt, fmaf(tt, fmaf(tt, fmaf(tt, 1.061405429f,
                             -1.453152027f), 1.421413741f), -0.284496736f), 0.254829592f);
          const float e = __builtin_amdgcn_exp2f(az * az * -1.4426950408889634f);
          float erfv = 1.0f - poly * e;
          erfv = (z < 0.f) ? -erfv : erfv;
          const float g = 0.5f * v * (1.0f + erfv);
          ((bf16*)Cout)[(size_t)row * N + col] = (bf16)g;
        } else {  // QKV fused: cols [0,1024)->Q std, [1024,2048)->K std, rest->Vt
          bf16* base = (bf16*)Cout;
          const int sect = col >> 10, c = col & 1023;
          if (sect < 2) {
            base[(size_t)sect * M_TOK * HDIM + (size_t)row * HDIM + c] = (bf16)v;
          } else {
            const int hh = c >> 6, dd = c & 63;
            const int bb = row >> 11, ss = row & 2047;
            base[(size_t)2 * M_TOK * HDIM +
                 (size_t)((bb * NHEAD + hh) * HD + dd) * SEQ + ss] = (bf16)v;
          }
        }
      }
    }
  }
}

// ---------------------------------------------------------------- flash attention (transposed, no-max)
__global__ __launch_bounds__(256)
void attn_kernel(const bf16* __restrict__ Q, const bf16* __restrict__ Kg,
                 const bf16* __restrict__ Vt, const int* __restrict__ mask,
                 bf16* __restrict__ Aout)
{
  __shared__ __align__(16) bf16 Ks[64 * 64];
  __shared__ __align__(16) bf16 Vs[64 * 64];
  __shared__ __align__(16) bf16 Ps[4][16 * 64];
  __shared__ float madd[64];

  const int t = threadIdx.x;
  const int wave = t >> 6, lane = t & 63;
  const int lm = lane & 15, qd = lane >> 4;
  const int bh = blockIdx.y;
  const int b = bh >> 4, h = bh & 15;
  const int q0 = blockIdx.x * 64;
  const int qg = q0 + wave * 16 + lm;
  bf16* Psw = Ps[wave];

  bf16x8 qf[2];
#pragma unroll
  for (int ks = 0; ks < 2; ++ks)
    qf[ks] = *(const bf16x8*)(Q + (size_t)(b * SEQ + qg) * HDIM + h * HD + ks * 32 + qd * 8);

  float l_lane = 0.f;
  f32x4 oacc[4] = {};

  const int srow = t >> 3, schk = t & 7;
  const float C = 0.1803368801f;  // log2(e)/8

  for (int kv0 = 0; kv0 < SEQ; kv0 += 64) {
#pragma unroll
    for (int r = 0; r < 2; ++r) {
      const int row = r * 32 + srow;
      const int g = schk ^ (row & 7);
      async_load16(Kg + (size_t)(b * SEQ + kv0 + row) * HDIM + h * HD + g * 8,
                   (bf16*)((char*)Ks + r * 4096 + t * 16));
      async_load16(Vt + (size_t)(bh * HD + row) * SEQ + kv0 + g * 8,
                   (bf16*)((char*)Vs + r * 4096 + t * 16));
    }
    if (t < 64) madd[t] = (mask[b * SEQ + kv0 + t] == 1) ? 0.f : -1.0e30f;
    __syncthreads();

    f32x4 sacc[4] = {};
#pragma unroll
    for (int ks = 0; ks < 2; ++ks) {
#pragma unroll
      for (int nt = 0; nt < 4; ++nt) {
        const int row = nt * 16 + lm;
        const int c = (ks * 4 + qd) ^ (row & 7);
        bf16x8 kf = *(const bf16x8*)(Ks + row * 64 + c * 8);
        sacc[nt] = __builtin_amdgcn_mfma_f32_16x16x32_bf16(kf, qf[ks], sacc[nt], 0, 0, 0);
      }
    }

#pragma unroll
    for (int nt = 0; nt < 4; ++nt) {
      f32x4 ma = *(const f32x4*)(madd + nt * 16 + qd * 4);
      bf16x4 pk;
#pragma unroll
      for (int r = 0; r < 4; ++r) {
        const float pv = __builtin_amdgcn_exp2f(fmaf(sacc[nt][r], C, ma[r]));
        l_lane += pv;
        pk[r] = (bf16)pv;
      }
      *(bf16x4*)((char*)Psw + lm * 128 +
                 (((nt * 2 + (qd >> 1)) ^ (lm & 7)) * 16) + (qd & 1) * 8) = pk;
    }

#pragma unroll
    for (int ks = 0; ks < 2; ++ks) {
      bf16x8 pf = *(const bf16x8*)((char*)Psw + lm * 128 + (((ks * 4 + qd) ^ (lm & 7)) * 16));
#pragma unroll
      for (int nt = 0; nt < 4; ++nt) {
        const int row = nt * 16 + lm;
        const int c = (ks * 4 + qd) ^ (row & 7);
        bf16x8 vf = *(const bf16x8*)(Vs + row * 64 + c * 8);
        oacc[nt] = __builtin_amdgcn_mfma_f32_16x16x32_bf16(vf, pf, oacc[nt], 0, 0, 0);
      }
    }
    __syncthreads();
  }

  float l = l_lane;
  l += __shfl_xor(l, 16, 64);
  l += __shfl_xor(l, 32, 64);
  const float inv = 1.0f / l;

#pragma unroll
  for (int nt = 0; nt < 4; ++nt) {
    bf16x4 ok;
#pragma unroll
    for (int r = 0; r < 4; ++r) ok[r] = (bf16)(oacc[nt][r] * inv);
    *(bf16x4*)((char*)Psw + lm * 128 +
               (((nt * 2 + (qd >> 1)) ^ (lm & 7)) * 16) + (qd & 1) * 8) = ok;
  }
#pragma unroll
  for (int rr = 0; rr < 2; ++rr) {
    const int ql = rr * 8 + (lane >> 3);
    const int cl = lane & 7;
    bf16x8 v = *(const bf16x8*)((char*)Psw + ql * 128 + ((cl ^ (ql & 7)) * 16));
    *(bf16x8*)(Aout + (size_t)(b * SEQ + q0 + wave * 16 + ql) * HDIM + h * HD + cl * 8) = v;
  }
}

// ------------------------------------------- layernorm over H=1024, summing NP split-K partials + bias
template<int NP, int OUT_BF16>
__global__ __launch_bounds__(256)
void ln_sum(const float* __restrict__ p, const float* __restrict__ bias,
            const float* __restrict__ gamma, const float* __restrict__ beta,
            void* __restrict__ out)
{
  const int row = blockIdx.x;
  const int t = threadIdx.x;
  f32x4 v = *(const f32x4*)(p + (size_t)row * HDIM + t * 4);
#pragma unroll
  for (int np = 1; np < NP; ++np) {
    f32x4 u = *(const f32x4*)(p + np * PSTRIDE + (size_t)row * HDIM + t * 4);
#pragma unroll
    for (int j = 0; j < 4; ++j) v[j] += u[j];
  }
  f32x4 bv0 = *(const f32x4*)(bias + t * 4);
#pragma unroll
  for (int j = 0; j < 4; ++j) v[j] += bv0[j];

  float s = v[0] + v[1] + v[2] + v[3];
  float s2 = v[0] * v[0] + v[1] * v[1] + v[2] * v[2] + v[3] * v[3];
#pragma unroll
  for (int d = 1; d < 64; d <<= 1) { s += __shfl_xor(s, d, 64); s2 += __shfl_xor(s2, d, 64); }
  __shared__ float ss[4], ss2[4];
  const int wave = t >> 6, lane = t & 63;
  if (lane == 0) { ss[wave] = s; ss2[wave] = s2; }
  __syncthreads();
  s = ss[0] + ss[1] + ss[2] + ss[3];
  s2 = ss2[0] + ss2[1] + ss2[2] + ss2[3];
  const float mean = s * (1.0f / HDIM);
  const float var = s2 * (1.0f / HDIM) - mean * mean;
  const float rstd = rsqrtf(var + 1e-12f);
  f32x4 gv = *(const f32x4*)(gamma + t * 4);
  f32x4 bv = *(const f32x4*)(beta + t * 4);
  f32x4 y;
#pragma unroll
  for (int j = 0; j < 4; ++j) y[j] = gv[j] * (v[j] - mean) * rstd + bv[j];
  if (OUT_BF16) {
    bf16x4 o;
#pragma unroll
    for (int j = 0; j < 4; ++j) o[j] = (bf16)y[j];
    *(bf16x4*)((bf16*)out + (size_t)row * HDIM + t * 4) = o;
  } else {
    *(f32x4*)((float*)out + (size_t)row * HDIM + t * 4) = y;
  }
}

// ---------------------------------------------------------------- launch
extern "C" void kernel_launch(void* const* d_in, const int* in_sizes, int n_in,
                              void* d_out, int out_size, void* d_ws, size_t ws_size,
                              hipStream_t stream)
{
  const float* x    = (const float*)d_in[0];
  const int*   am   = (const int*)d_in[1];
  const float* Wq   = (const float*)d_in[2];
  const float* bq   = (const float*)d_in[3];
  const float* Wk   = (const float*)d_in[4];
  const float* bk   = (const float*)d_in[5];
  const float* Wv   = (const float*)d_in[6];
  const float* bv   = (const float*)d_in[7];
  const float* Wo   = (const float*)d_in[8];
  const float* bo   = (const float*)d_in[9];
  const float* ln1g = (const float*)d_in[10];
  const float* ln1b = (const float*)d_in[11];
  const float* W1   = (const float*)d_in[12];
  const float* b1   = (const float*)d_in[13];
  const float* W2   = (const float*)d_in[14];
  const float* b2   = (const float*)d_in[15];
  const float* ln2g = (const float*)d_in[16];
  const float* ln2b = (const float*)d_in[17];

  char* ws = (char*)d_ws;
  const size_t MB = 1ull << 20;
  bf16*  W1T  = (bf16*)(ws + 0 * MB);    // 8 MiB
  bf16*  W2T  = (bf16*)(ws + 8 * MB);    // 8 MiB
  bf16*  Xb   = (bf16*)(ws + 16 * MB);   // 8 MiB
  bf16*  QKVT = (bf16*)(ws + 24 * MB);   // 8 MiB: WqT,WkT,WvT,WoT contiguous
  bf16*  WoT  = QKVT + (size_t)3 * HDIM * HDIM;
  bf16*  Qb   = (bf16*)(ws + 33 * MB);   // Q,K std then Vt (contiguous for QKV epi)
  bf16*  Kb   = (bf16*)(ws + 41 * MB);
  bf16*  Vtb  = (bf16*)(ws + 49 * MB);
  bf16*  Ab   = (bf16*)(ws + 16 * MB);   // reuse Xb (dead after QKV)
  float* Pw   = (float*)(ws + 33 * MB);  // Wo partials: 33-65 (Q/K/Vt dead)
  bf16*  L1   = (bf16*)(ws + 65 * MB);   // 8 MiB
  bf16*  F1   = (bf16*)(ws + 16 * MB);   // 32 MiB: 16-48
  float* Pf   = (float*)(ws + 48 * MB);  // FFN2 partials: 48 + 16*zf

  prep_kernel<<<dim3(32, 32, 13), 256, 0, stream>>>(x, Wq, Wk, Wv, Wo, W1, W2,
                                                    Xb, QKVT, W1T, W2T);

  gemm_bt<3><<<dim3(3072 / 128, M_TOK / 128, 1), 256, 0, stream>>>(
      Xb, QKVT, bq, bk, bv, Qb, M_TOK, 3072, HDIM, HDIM);

  attn_kernel<<<dim3(SEQ / 64, BATCH * NHEAD), 256, 0, stream>>>(Qb, Kb, Vtb, am, Ab);

  gemm_bt<1><<<dim3(HDIM / 128, M_TOK / 128, 2), 256, 0, stream>>>(
      Ab, WoT, nullptr, nullptr, nullptr, Pw, M_TOK, HDIM, HDIM, 512);
  ln_sum<2, 1><<<M_TOK, 256, 0, stream>>>(Pw, bo, ln1g, ln1b, L1);

  gemm_bt<2><<<dim3(FFDIM / 128, M_TOK / 128, 1), 256, 0, stream>>>(
      L1, W1T, b1, nullptr, nullptr, F1, M_TOK, FFDIM, HDIM, HDIM);

  // FFN2: split-K z=4 if workspace allows (partials end at 48+64=112 MiB), else z=2
  if (ws_size >= 113 * MB) {
    gemm_bt<1><<<dim3(HDIM / 128, M_TOK / 128, 4), 256, 0, stream>>>(
        F1, W2T, nullptr, nullptr, nullptr, Pf, M_TOK, HDIM, FFDIM, 1024);
    ln_sum<4, 0><<<M_TOK, 256, 0, stream>>>(Pf, b2, ln2g, ln2b, (float*)d_out);
  } else {
    gemm_bt<1><<<dim3(HDIM / 128, M_TOK / 128, 2), 256, 0, stream>>>(
        F1, W2T, nullptr, nullptr, nullptr, Pf, M_TOK, HDIM, FFDIM, 2048);
    ln_sum<2, 0><<<M_TOK, 256, 0, stream>>>(Pf, b2, ln2g, ln2b, (float*)d_out);
  }
}